// Round 2
// 706.300 us; speedup vs baseline: 1.0073x; 1.0073x over previous
//
#include <hip/hip_runtime.h>
#include <hip/hip_fp16.h>

#define RES 512
#define FEAT 32
#define NPLANES 6
#define XT 128
#define TP (XT + 4)   // LDS tile pitch (floats): 132 -> 528 B rows (16B-aligned), bank shift 4/row

typedef float f4 __attribute__((ext_vector_type(4)));

// ---------------------------------------------------------------------------
// Transpose + downconvert: [p][c][y][x] fp32 -> [p][y][x][c] fp16.
// Block = (plane, row, 128-wide x tile). Reads 512 B runs per channel,
// writes 8 KB contiguous fp16 per block.
// NT loads on the fp32 source: it is read exactly once, and letting it
// allocate in L2/L3 evicts the fp16 T we are about to sample from.
// T stores stay cacheable — we WANT T resident in the 256 MiB L3.
// ---------------------------------------------------------------------------
__global__ __launch_bounds__(256) void transpose_fp16_kernel(
    const float* __restrict__ in, __half* __restrict__ out)
{
    __shared__ float tile[FEAT][TP];
    const int b  = blockIdx.x;
    const int xt = b & 3;              // 4 tiles of 128 along x
    const int y  = (b >> 2) & (RES - 1);
    const int p  = b >> 11;            // 512*4 = 2048 blocks per plane
    const int xbase = xt << 7;

    const size_t pb = (size_t)p * ((size_t)FEAT * RES * RES) + (size_t)y * RES + xbase;
    #pragma unroll
    for (int j = 0; j < 4; ++j) {
        const int f  = threadIdx.x + j * 256;   // float4 index 0..1023
        const int c  = f >> 5;                  // 32 float4 per 128-wide row
        const int x4 = (f & 31) << 2;
        const f4 v = __builtin_nontemporal_load(
            (const f4*)(in + pb + (size_t)c * (RES * RES) + x4));
        *(f4*)&tile[c][x4] = v;
    }
    __syncthreads();

    // Output element k (0..4095): x = k>>5, c = k&31. Thread t covers
    // k = 16t..16t+15  =>  column m = t>>1, channels c0..c0+15, c0 = (t&1)*16.
    const int m  = threadIdx.x >> 1;
    const int c0 = (threadIdx.x & 1) << 4;
    union { __half h[16]; float4 f4v[2]; } u;
    #pragma unroll
    for (int j = 0; j < 16; ++j)
        u.h[j] = __float2half_rn(tile[c0 + j][m]);

    const size_t ob = (((size_t)p * RES + y) * RES + xbase) * FEAT
                    + (size_t)threadIdx.x * 16;
    *(float4*)(out + ob)     = u.f4v[0];
    *(float4*)(out + ob + 8) = u.f4v[1];
}

// ---------------------------------------------------------------------------
// Sampler: 4 threads per point, 8 channels per thread. Each tap is a 16 B
// load (8 halves); 4 lanes of a point form a 64 B contiguous segment.
// Output stores are non-temporal: 256 MB of write-once data must not evict
// the 96 MiB plane set from L2/L3 (FETCH was ~10x compulsory without this).
// ---------------------------------------------------------------------------
__device__ __forceinline__ void unpack8(const float4 r, float* o)
{
    const __half2* h = (const __half2*)&r;
    float2 p;
    p = __half22float2(h[0]); o[0] = p.x; o[1] = p.y;
    p = __half22float2(h[1]); o[2] = p.x; o[3] = p.y;
    p = __half22float2(h[2]); o[4] = p.x; o[5] = p.y;
    p = __half22float2(h[3]); o[6] = p.x; o[7] = p.y;
}

template <int XIq, int YIq, int Q>
__device__ __forceinline__ void sample_plane(
    const float* d, const __half* __restrict__ planes, int sub, float* f)
{
    const float u = d[XIq];
    const float v = d[YIq];
    float fx = fminf(fmaxf((u + 1.0f) * 0.5f * 511.0f, 0.0f), 511.0f);
    float fy = fminf(fmaxf((v + 1.0f) * 0.5f * 511.0f, 0.0f), 511.0f);
    const float x0f = floorf(fx), y0f = floorf(fy);
    const float wx = fx - x0f,   wy = fy - y0f;
    const int x0 = (int)x0f, y0 = (int)y0f;
    const int x1 = min(x0 + 1, RES - 1), y1 = min(y0 + 1, RES - 1);
    const float w00 = (1.0f - wx) * (1.0f - wy);
    const float w01 = wx * (1.0f - wy);
    const float w10 = (1.0f - wx) * wy;
    const float w11 = wx * wy;

    const __half* P = planes + ((size_t)Q << 23) + (sub << 3);  // plane + channel-group base
    const int r0 = y0 << 9, r1 = y1 << 9;
    const float4 a00 = *(const float4*)(P + ((size_t)(r0 + x0) << 5));
    const float4 a01 = *(const float4*)(P + ((size_t)(r0 + x1) << 5));
    const float4 a10 = *(const float4*)(P + ((size_t)(r1 + x0) << 5));
    const float4 a11 = *(const float4*)(P + ((size_t)(r1 + x1) << 5));

    float v00[8], v01[8], v10[8], v11[8];
    unpack8(a00, v00); unpack8(a01, v01); unpack8(a10, v10); unpack8(a11, v11);
    #pragma unroll
    for (int i = 0; i < 8; ++i)
        f[i] = v00[i] * w00 + v01[i] * w01 + v10[i] * w10 + v11[i] * w11;
}

__global__ __launch_bounds__(256) void sample_fp16_kernel(
    const float* __restrict__ pts, const float* __restrict__ tm,
    const __half* __restrict__ planes, float* __restrict__ out, int npts)
{
    const int t  = blockIdx.x * 256 + threadIdx.x;
    const int pt = t >> 2;
    const int sub = t & 3;
    if (pt >= npts) return;

    float d[4];
    d[0] = (__builtin_nontemporal_load(pts + (size_t)pt * 3 + 0) + 1.6f) / 3.2f * 2.0f - 1.0f;
    d[1] = (__builtin_nontemporal_load(pts + (size_t)pt * 3 + 1) + 1.6f) / 3.2f * 2.0f - 1.0f;
    d[2] = (__builtin_nontemporal_load(pts + (size_t)pt * 3 + 2) + 1.6f) / 3.2f * 2.0f - 1.0f;
    d[3] = __builtin_nontemporal_load(tm + pt) * 2.0f - 1.0f;

    float f[8], sp[8], st[8];

    // space = (f0 * f1) * f3   (planes 0:(x,y)=(d0,d1), 1:(d0,d2), 3:(d1,d2))
    sample_plane<0, 1, 0>(d, planes, sub, sp);
    sample_plane<0, 2, 1>(d, planes, sub, f);
    #pragma unroll
    for (int i = 0; i < 8; ++i) sp[i] *= f[i];
    sample_plane<1, 2, 3>(d, planes, sub, f);
    #pragma unroll
    for (int i = 0; i < 8; ++i) sp[i] *= f[i];
    {
        float* o = out + (size_t)pt * FEAT + (sub << 3);
        __builtin_nontemporal_store(*(const f4*)&sp[0], (f4*)o);
        __builtin_nontemporal_store(*(const f4*)&sp[4], (f4*)(o + 4));
    }

    // spacetime = (f2 * f4) * f5  (planes 2:(d3,d0), 4:(d3,d1), 5:(d3,d2))
    sample_plane<3, 0, 2>(d, planes, sub, st);
    sample_plane<3, 1, 4>(d, planes, sub, f);
    #pragma unroll
    for (int i = 0; i < 8; ++i) st[i] *= f[i];
    sample_plane<3, 2, 5>(d, planes, sub, f);
    #pragma unroll
    for (int i = 0; i < 8; ++i) st[i] *= f[i];
    {
        float* o = out + (size_t)npts * FEAT + (size_t)pt * FEAT + (sub << 3);
        __builtin_nontemporal_store(*(const f4*)&st[0], (f4*)o);
        __builtin_nontemporal_store(*(const f4*)&st[4], (f4*)(o + 4));
    }
}

// ---------------------------------------------------------------------------
// Fallback (ws too small): sample original [p][c][y][x] fp32 layout directly.
// ---------------------------------------------------------------------------
__global__ __launch_bounds__(256) void sample_fallback_kernel(
    const float* __restrict__ pts, const float* __restrict__ tm,
    const float* __restrict__ planes, float* __restrict__ out, int npts)
{
    const int t  = blockIdx.x * 256 + threadIdx.x;
    const int pt = t >> 5;
    const int c  = t & 31;
    if (pt >= npts) return;

    float d[4];
    d[0] = (pts[(size_t)pt * 3 + 0] + 1.6f) / 3.2f * 2.0f - 1.0f;
    d[1] = (pts[(size_t)pt * 3 + 1] + 1.6f) / 3.2f * 2.0f - 1.0f;
    d[2] = (pts[(size_t)pt * 3 + 2] + 1.6f) / 3.2f * 2.0f - 1.0f;
    d[3] = tm[pt] * 2.0f - 1.0f;

    const int xi[NPLANES] = {0, 0, 3, 1, 3, 3};
    const int yi[NPLANES] = {1, 2, 0, 2, 1, 2};
    float f[NPLANES];
    #pragma unroll
    for (int q = 0; q < NPLANES; ++q) {
        const float u = d[xi[q]], v = d[yi[q]];
        float fx = fminf(fmaxf((u + 1.0f) * 0.5f * 511.0f, 0.0f), 511.0f);
        float fy = fminf(fmaxf((v + 1.0f) * 0.5f * 511.0f, 0.0f), 511.0f);
        const float x0f = floorf(fx), y0f = floorf(fy);
        const float wx = fx - x0f, wy = fy - y0f;
        const int x0 = (int)x0f, y0 = (int)y0f;
        const int x1 = min(x0 + 1, RES - 1), y1 = min(y0 + 1, RES - 1);
        const float* P = planes + ((size_t)(q * FEAT + c) << 18);
        const int r0 = y0 << 9, r1 = y1 << 9;
        f[q] = P[r0 + x0] * ((1.0f - wx) * (1.0f - wy)) + P[r0 + x1] * (wx * (1.0f - wy)) +
               P[r1 + x0] * ((1.0f - wx) * wy)          + P[r1 + x1] * (wx * wy);
    }
    out[(size_t)pt * FEAT + c] = f[0] * f[1] * f[3];
    out[(size_t)npts * FEAT + (size_t)pt * FEAT + c] = f[2] * f[4] * f[5];
}

extern "C" void kernel_launch(void* const* d_in, const int* in_sizes, int n_in,
                              void* d_out, int out_size, void* d_ws, size_t ws_size,
                              hipStream_t stream) {
    const float* pts    = (const float*)d_in[0];
    const float* tm     = (const float*)d_in[1];
    const float* planes = (const float*)d_in[2];
    float* out = (float*)d_out;
    const int npts = in_sizes[0] / 3;

    const size_t need = (size_t)NPLANES * FEAT * RES * RES * sizeof(__half);  // 96 MiB
    if (ws_size >= need) {
        __half* T = (__half*)d_ws;
        transpose_fp16_kernel<<<NPLANES * RES * 4, 256, 0, stream>>>(planes, T);
        const int blocks = (npts * 4 + 255) / 256;
        sample_fp16_kernel<<<blocks, 256, 0, stream>>>(pts, tm, T, out, npts);
    } else {
        const int blocks = (npts * 32 + 255) / 256;
        sample_fallback_kernel<<<blocks, 256, 0, stream>>>(pts, tm, planes, out, npts);
    }
}

// Round 3
// 688.421 us; speedup vs baseline: 1.0335x; 1.0260x over previous
//
#include <hip/hip_runtime.h>
#include <hip/hip_fp16.h>

#define RES 512
#define FEAT 32
#define NPLANES 6
#define TPH (RES + 8)   // fp16 LDS row pitch (halves): 520 -> odd word stride, <=2-way banks

typedef float f4 __attribute__((ext_vector_type(4)));

// ---------------------------------------------------------------------------
// Transpose + downconvert: [p][c][y][x] fp32 -> [p][y][x][c] fp16.
// v2: block = (plane, full row y). Reads 2 KB contiguous per channel-stream
// (1 KB per wave-load), converts to fp16 BEFORE LDS (33 KB -> 4 blocks/CU),
// writes 32 KB contiguous per block. Old version read 512 B runs at 1 MiB
// stride and ran ~7x off roofline (~348 us for ~300 MB of traffic).
// NT loads on the fp32 source: read exactly once; keep T cacheable.
// ---------------------------------------------------------------------------
__global__ __launch_bounds__(256) void transpose_fp16_kernel(
    const float* __restrict__ in, __half* __restrict__ out)
{
    __shared__ __half tile[FEAT][TPH];
    const int b = blockIdx.x;
    const int y = b & (RES - 1);
    const int p = b >> 9;               // 512 blocks per plane

    const size_t pb = (size_t)p * ((size_t)FEAT * RES * RES) + (size_t)y * RES;
    #pragma unroll
    for (int j = 0; j < 16; ++j) {
        const int f  = threadIdx.x + j * 256;   // float4 index 0..4095
        const int c  = f >> 7;                  // 128 float4 per 512-wide row
        const int x4 = (f & 127) << 2;
        const f4 v = __builtin_nontemporal_load(
            (const f4*)(in + pb + (size_t)c * (RES * RES) + x4));
        union { __half h[4]; float2 f2; } u;
        u.h[0] = __float2half_rn(v[0]);
        u.h[1] = __float2half_rn(v[1]);
        u.h[2] = __float2half_rn(v[2]);
        u.h[3] = __float2half_rn(v[3]);
        *(float2*)&tile[c][x4] = u.f2;          // 8 B LDS write, minimal banking
    }
    __syncthreads();

    // Phase 2: thread t covers x = (t>>1) + 128*it, channels c0..c0+15.
    // LDS reads are u16, <=2-way word-shared across lanes (free on gfx950).
    const int xl = threadIdx.x >> 1;
    const int c0 = (threadIdx.x & 1) << 4;
    const size_t ob0 = ((size_t)(p * RES + y) * RES) * FEAT + c0;
    #pragma unroll
    for (int it = 0; it < 4; ++it) {
        const int x = xl + (it << 7);
        union { __half h[16]; float4 q[2]; } u;
        #pragma unroll
        for (int j = 0; j < 16; ++j)
            u.h[j] = tile[c0 + j][x];
        __half* o = out + ob0 + (size_t)x * FEAT;
        *(float4*)o       = u.q[0];
        *(float4*)(o + 8) = u.q[1];
    }
}

// ---------------------------------------------------------------------------
// Sampler: 4 threads per point, 8 channels per thread. v2: compute all 6
// planes' addresses + weights first, then issue ALL 24 tap loads before any
// consumption (MLP 24/wave vs 4/wave). In-order returns let plane q's
// combine overlap planes q+1.. loads still in flight.
// ---------------------------------------------------------------------------
__device__ __forceinline__ void unpack8(const float4 r, float* o)
{
    const __half2* h = (const __half2*)&r;
    float2 p;
    p = __half22float2(h[0]); o[0] = p.x; o[1] = p.y;
    p = __half22float2(h[1]); o[2] = p.x; o[3] = p.y;
    p = __half22float2(h[2]); o[4] = p.x; o[5] = p.y;
    p = __half22float2(h[3]); o[6] = p.x; o[7] = p.y;
}

__global__ __launch_bounds__(256) void sample_fp16_kernel(
    const float* __restrict__ pts, const float* __restrict__ tm,
    const __half* __restrict__ planes, float* __restrict__ out, int npts)
{
    const int t  = blockIdx.x * 256 + threadIdx.x;
    const int pt = t >> 2;
    const int sub = t & 3;
    if (pt >= npts) return;

    float d[4];
    d[0] = (pts[(size_t)pt * 3 + 0] + 1.6f) / 3.2f * 2.0f - 1.0f;
    d[1] = (pts[(size_t)pt * 3 + 1] + 1.6f) / 3.2f * 2.0f - 1.0f;
    d[2] = (pts[(size_t)pt * 3 + 2] + 1.6f) / 3.2f * 2.0f - 1.0f;
    d[3] = tm[pt] * 2.0f - 1.0f;

    const int xi[NPLANES] = {0, 0, 3, 1, 3, 3};
    const int yi[NPLANES] = {1, 2, 0, 2, 1, 2};

    // Phase A: all addresses + weights (pure VALU, no memory).
    int   off[NPLANES][4];
    float w[NPLANES][4];
    #pragma unroll
    for (int q = 0; q < NPLANES; ++q) {
        const float u = d[xi[q]];
        const float v = d[yi[q]];
        float fx = fminf(fmaxf((u + 1.0f) * 0.5f * 511.0f, 0.0f), 511.0f);
        float fy = fminf(fmaxf((v + 1.0f) * 0.5f * 511.0f, 0.0f), 511.0f);
        const float x0f = floorf(fx), y0f = floorf(fy);
        const float wx = fx - x0f,   wy = fy - y0f;
        const int x0 = (int)x0f, y0 = (int)y0f;
        const int x1 = min(x0 + 1, RES - 1), y1 = min(y0 + 1, RES - 1);
        const int r0 = y0 << 9, r1 = y1 << 9;
        off[q][0] = (r0 + x0) << 5;
        off[q][1] = (r0 + x1) << 5;
        off[q][2] = (r1 + x0) << 5;
        off[q][3] = (r1 + x1) << 5;
        w[q][0] = (1.0f - wx) * (1.0f - wy);
        w[q][1] = wx * (1.0f - wy);
        w[q][2] = (1.0f - wx) * wy;
        w[q][3] = wx * wy;
    }

    // Phase B: issue all 24 tap loads back-to-back.
    float4 a[NPLANES][4];
    #pragma unroll
    for (int q = 0; q < NPLANES; ++q) {
        const __half* P = planes + ((size_t)q << 23) + (sub << 3);
        #pragma unroll
        for (int k = 0; k < 4; ++k)
            a[q][k] = *(const float4*)(P + off[q][k]);
    }

    // Phase C: per-plane bilinear combine (overlaps later loads in flight).
    float fq[NPLANES][8];
    #pragma unroll
    for (int q = 0; q < NPLANES; ++q) {
        float v00[8], v01[8], v10[8], v11[8];
        unpack8(a[q][0], v00); unpack8(a[q][1], v01);
        unpack8(a[q][2], v10); unpack8(a[q][3], v11);
        #pragma unroll
        for (int i = 0; i < 8; ++i)
            fq[q][i] = v00[i] * w[q][0] + v01[i] * w[q][1]
                     + v10[i] * w[q][2] + v11[i] * w[q][3];
    }

    {
        float sp[8], st[8];
        #pragma unroll
        for (int i = 0; i < 8; ++i) {
            sp[i] = fq[0][i] * fq[1][i] * fq[3][i];
            st[i] = fq[2][i] * fq[4][i] * fq[5][i];
        }
        float4* o = (float4*)(out + (size_t)pt * FEAT + (sub << 3));
        o[0] = *(float4*)&sp[0];
        o[1] = *(float4*)&sp[4];
        float4* o2 = (float4*)(out + (size_t)npts * FEAT + (size_t)pt * FEAT + (sub << 3));
        o2[0] = *(float4*)&st[0];
        o2[1] = *(float4*)&st[4];
    }
}

// ---------------------------------------------------------------------------
// Fallback (ws too small): sample original [p][c][y][x] fp32 layout directly.
// ---------------------------------------------------------------------------
__global__ __launch_bounds__(256) void sample_fallback_kernel(
    const float* __restrict__ pts, const float* __restrict__ tm,
    const float* __restrict__ planes, float* __restrict__ out, int npts)
{
    const int t  = blockIdx.x * 256 + threadIdx.x;
    const int pt = t >> 5;
    const int c  = t & 31;
    if (pt >= npts) return;

    float d[4];
    d[0] = (pts[(size_t)pt * 3 + 0] + 1.6f) / 3.2f * 2.0f - 1.0f;
    d[1] = (pts[(size_t)pt * 3 + 1] + 1.6f) / 3.2f * 2.0f - 1.0f;
    d[2] = (pts[(size_t)pt * 3 + 2] + 1.6f) / 3.2f * 2.0f - 1.0f;
    d[3] = tm[pt] * 2.0f - 1.0f;

    const int xi[NPLANES] = {0, 0, 3, 1, 3, 3};
    const int yi[NPLANES] = {1, 2, 0, 2, 1, 2};
    float f[NPLANES];
    #pragma unroll
    for (int q = 0; q < NPLANES; ++q) {
        const float u = d[xi[q]], v = d[yi[q]];
        float fx = fminf(fmaxf((u + 1.0f) * 0.5f * 511.0f, 0.0f), 511.0f);
        float fy = fminf(fmaxf((v + 1.0f) * 0.5f * 511.0f, 0.0f), 511.0f);
        const float x0f = floorf(fx), y0f = floorf(fy);
        const float wx = fx - x0f, wy = fy - y0f;
        const int x0 = (int)x0f, y0 = (int)y0f;
        const int x1 = min(x0 + 1, RES - 1), y1 = min(y0 + 1, RES - 1);
        const float* P = planes + ((size_t)(q * FEAT + c) << 18);
        const int r0 = y0 << 9, r1 = y1 << 9;
        f[q] = P[r0 + x0] * ((1.0f - wx) * (1.0f - wy)) + P[r0 + x1] * (wx * (1.0f - wy)) +
               P[r1 + x0] * ((1.0f - wx) * wy)          + P[r1 + x1] * (wx * wy);
    }
    out[(size_t)pt * FEAT + c] = f[0] * f[1] * f[3];
    out[(size_t)npts * FEAT + (size_t)pt * FEAT + c] = f[2] * f[4] * f[5];
}

extern "C" void kernel_launch(void* const* d_in, const int* in_sizes, int n_in,
                              void* d_out, int out_size, void* d_ws, size_t ws_size,
                              hipStream_t stream) {
    const float* pts    = (const float*)d_in[0];
    const float* tm     = (const float*)d_in[1];
    const float* planes = (const float*)d_in[2];
    float* out = (float*)d_out;
    const int npts = in_sizes[0] / 3;

    const size_t need = (size_t)NPLANES * FEAT * RES * RES * sizeof(__half);  // 96 MiB
    if (ws_size >= need) {
        __half* T = (__half*)d_ws;
        transpose_fp16_kernel<<<NPLANES * RES, 256, 0, stream>>>(planes, T);
        const int blocks = (npts * 4 + 255) / 256;
        sample_fp16_kernel<<<blocks, 256, 0, stream>>>(pts, tm, T, out, npts);
    } else {
        const int blocks = (npts * 32 + 255) / 256;
        sample_fallback_kernel<<<blocks, 256, 0, stream>>>(pts, tm, planes, out, npts);
    }
}